// Round 4
// baseline (302.032 us; speedup 1.0000x reference)
//
#include <hip/hip_runtime.h>
#include <hip/hip_bf16.h>

typedef float f32x4 __attribute__((ext_vector_type(4)));
typedef __bf16 bf16x8 __attribute__((ext_vector_type(8)));
typedef unsigned short ushort8 __attribute__((ext_vector_type(8)));

#define DEVINL __device__ __forceinline__

DEVINL void gload_lds16(const void* g, void* l) {
  __builtin_amdgcn_global_load_lds(
      (const __attribute__((address_space(1))) void*)g,
      (__attribute__((address_space(3))) void*)l, 16, 0, 0);
}

DEVINL unsigned short f2bf(float f) {
  unsigned int x = __float_as_uint(f);
  x += 0x7fffu + ((x >> 16) & 1u);
  return (unsigned short)(x >> 16);
}

// Stage tiles whose rows are 64 bytes (32 bf16 K-slice). 512-thread blocks.
// LDS[r][c] = global[r][c ^ ((r>>1)&3)] (16B chunks); linear LDS dest.
template <int ITERS>
DEVINL void stage_rows64(const char* g, int pitch, char* lds, int tid, int ktb) {
#pragma unroll
  for (int p = 0; p < ITERS; ++p) {
    int idx = p * 512 + tid;
    int r = idx >> 2, c = idx & 3;
    int cs = c ^ ((r >> 1) & 3);
    gload_lds16(g + (size_t)r * pitch + ktb + cs * 16, lds + idx * 16);
  }
}

DEVINL bf16x8 fragB32(const char* lds, int r, int kg) {
  int c = kg ^ ((r >> 1) & 3);
  return *(const bf16x8*)(lds + r * 64 + c * 16);
}

// ---------------- prep_x: x f32 -> bf16 ----------------
__global__ __launch_bounds__(256) void prep_x(const float* __restrict__ X,
                                              unsigned short* __restrict__ Xb) {
  size_t i = ((size_t)blockIdx.x * 256 + threadIdx.x) * 8;
  f32x4 a = *(const f32x4*)(X + i);
  f32x4 c = *(const f32x4*)(X + i + 4);
  uint4 pv;
  pv.x = (unsigned)f2bf(a[0]) | ((unsigned)f2bf(a[1]) << 16);
  pv.y = (unsigned)f2bf(a[2]) | ((unsigned)f2bf(a[3]) << 16);
  pv.z = (unsigned)f2bf(c[0]) | ((unsigned)f2bf(c[1]) << 16);
  pv.w = (unsigned)f2bf(c[2]) | ((unsigned)f2bf(c[3]) << 16);
  *(uint4*)(Xb + i) = pv;
}

// ---------------- prep_w: Wkv -> bf16 (bids 0..127); WqT transpose (bids 128..131) ----------------
__global__ __launch_bounds__(256) void prep_w(const float* __restrict__ Wqkv,
                                              unsigned short* __restrict__ Wkvb,
                                              unsigned short* __restrict__ WqT) {
  __shared__ __align__(16) unsigned short l[256 * 72];
  int bid = blockIdx.x, t = threadIdx.x;
  if (bid < 128) {
    size_t i = (size_t)bid * 1024 + t * 4;
    f32x4 v = *(const f32x4*)(Wqkv + 65536 + i);
    uint2 pv;
    pv.x = (unsigned)f2bf(v[0]) | ((unsigned)f2bf(v[1]) << 16);
    pv.y = (unsigned)f2bf(v[2]) | ((unsigned)f2bf(v[3]) << 16);
    *(uint2*)(Wkvb + i) = pv;
  } else {
    int bb = bid - 128;  // e-rows [bb*64, bb*64+64)
    for (int r = 0; r < 64; ++r)
      l[t * 72 + r] = f2bf(Wqkv[(size_t)(bb * 64 + r) * 256 + t]);
    __syncthreads();
#pragma unroll
    for (int c8 = 0; c8 < 8; ++c8) {
      ushort8 v = *(const ushort8*)(l + t * 72 + c8 * 8);
      *(ushort8*)(WqT + (size_t)t * 256 + bb * 64 + c8 * 8) = v;
    }
  }
}

// ---------------- kv_dots: kv = x@Wkv^T, norm(d=32), dots += k^T v  (fused) ----------------
// Writes ONLY atomic partials [8][4][8][32][32]. BM=128 tokens, BN=512 (all kv).
__global__ __launch_bounds__(512) void kv_dots(
    const unsigned short* __restrict__ Xb, const unsigned short* __restrict__ Wkvb,
    float* __restrict__ partial) {
  __shared__ __align__(16) char lds[81920];
  char* AsB[2] = {lds, lds + 8192};
  char* BsB[2] = {lds + 16384, lds + 49152};
  char* kT = lds;           // reused after GEMM: [128 d][128 tok] bf16, swizzled
  char* vT = lds + 32768;
  int bid = blockIdx.x;
  int swz = (bid & 7) * 64 + (bid >> 3);   // 512 = 8*64 bijective XCD swizzle
  int tid = threadIdx.x, lane = tid & 63, wid = tid >> 6;
  int wm = wid >> 2, wn = wid & 3;         // 2x4 waves, 64 rows x 128 cols each
  int lr = lane & 15, kg = lane >> 4;
  const char* Ag = (const char*)Xb + (size_t)swz * 128 * 512;
  const char* Bg = (const char*)Wkvb;
  f32x4 acc[4][8] = {};
  stage_rows64<1>(Ag, 512, AsB[0], tid, 0);
  stage_rows64<4>(Bg, 512, BsB[0], tid, 0);
  __syncthreads();
  for (int kt = 0; kt < 8; ++kt) {
    int cur = kt & 1;
    if (kt < 7) {
      stage_rows64<1>(Ag, 512, AsB[cur ^ 1], tid, (kt + 1) * 64);
      stage_rows64<4>(Bg, 512, BsB[cur ^ 1], tid, (kt + 1) * 64);
    }
    bf16x8 af[4], bfr[8];
#pragma unroll
    for (int i = 0; i < 4; ++i) af[i] = fragB32(AsB[cur], wm * 64 + i * 16 + lr, kg);
#pragma unroll
    for (int j = 0; j < 8; ++j) bfr[j] = fragB32(BsB[cur], wn * 128 + j * 16 + lr, kg);
#pragma unroll
    for (int i = 0; i < 4; ++i)
#pragma unroll
      for (int j = 0; j < 8; ++j)
        acc[i][j] = __builtin_amdgcn_mfma_f32_16x16x32_bf16(bfr[j], af[i], acc[i][j], 0, 0, 0);
    __syncthreads();
  }
  // ---- normalize over d=32 groups (cols g*32..g*32+31 within wave span) in f32 ----
  unsigned short nv[4][8][4];
#pragma unroll
  for (int i = 0; i < 4; ++i) {
#pragma unroll
    for (int g = 0; g < 4; ++g) {
      float s = 0.f, ss = 0.f;
#pragma unroll
      for (int jj = 0; jj < 2; ++jj) {
        f32x4 tq = acc[i][g * 2 + jj];
#pragma unroll
        for (int q = 0; q < 4; ++q) { s += tq[q]; ss += tq[q] * tq[q]; }
      }
      s += __shfl_xor(s, 16, 64);  s += __shfl_xor(s, 32, 64);
      ss += __shfl_xor(ss, 16, 64); ss += __shfl_xor(ss, 32, 64);
      float mean = s * (1.0f / 32.0f);
      float var = ss * (1.0f / 32.0f) - mean * mean;
      float rs = rsqrtf(var + 1e-5f);
#pragma unroll
      for (int jj = 0; jj < 2; ++jj)
#pragma unroll
        for (int q = 0; q < 4; ++q)
          nv[i][g * 2 + jj][q] = f2bf((acc[i][g * 2 + jj][q] - mean) * rs);
    }
  }
  // ---- transposed store to LDS + per-head dots via MFMA (contract over tokens) ----
  auto writeT = [&]() {
    char* base = (wn < 2) ? kT : vT;
#pragma unroll
    for (int i = 0; i < 4; ++i) {
      int tok = wm * 64 + i * 16 + lr;
#pragma unroll
      for (int j = 0; j < 8; ++j)
#pragma unroll
        for (int q = 0; q < 4; ++q) {
          int d = j * 16 + kg * 4 + q;
          int byte = (d * 256 + tok * 2) ^ ((d & 7) << 4);
          *(unsigned short*)(base + byte) = nv[i][j][q];
        }
    }
  };
  int bsel = swz >> 7;  // batch (128 blocks per batch)
  auto dots_acc = [&](int hb) {
    int g = wid & 3, th = wid >> 2;  // head-in-half, token-half
    f32x4 dacc[2][2] = {};
#pragma unroll
    for (int ks = 0; ks < 2; ++ks) {
      int tb = th * 128 + ks * 64 + kg * 16;  // token byte offset
      bf16x8 kf[2], vf[2];
#pragma unroll
      for (int dt = 0; dt < 2; ++dt) {
        int d = g * 32 + dt * 16 + lr;
        kf[dt] = *(const bf16x8*)(kT + ((d * 256 + tb) ^ ((d & 7) << 4)));
      }
#pragma unroll
      for (int et = 0; et < 2; ++et) {
        int e = g * 32 + et * 16 + lr;
        vf[et] = *(const bf16x8*)(vT + ((e * 256 + tb) ^ ((e & 7) << 4)));
      }
#pragma unroll
      for (int dt = 0; dt < 2; ++dt)
#pragma unroll
        for (int et = 0; et < 2; ++et)
          dacc[dt][et] = __builtin_amdgcn_mfma_f32_16x16x32_bf16(vf[et], kf[dt], dacc[dt][et], 0, 0, 0);
    }
    float* dout = partial + (size_t)(bid & 7) * 32768 + ((size_t)bsel * 8 + hb + g) * 1024;
    // D[r][c]: r = v-side (e) = kg*4+q, c = k-side (d) = lr
#pragma unroll
    for (int dt = 0; dt < 2; ++dt)
#pragma unroll
      for (int et = 0; et < 2; ++et)
#pragma unroll
        for (int q = 0; q < 4; ++q) {
          int d = dt * 16 + lr;
          int e = et * 16 + kg * 4 + q;
          atomicAdd(dout + d * 32 + e, dacc[dt][et][q]);
        }
  };
  if ((wn & 1) == 0) writeT();   // heads 0..3 (k: wn=0, v: wn=2)
  __syncthreads();
  dots_acc(0);
  __syncthreads();
  if ((wn & 1) == 1) writeT();   // heads 4..7
  __syncthreads();
  dots_acc(4);
}

// ---------------- reduce 8 partial copies -> dots ----------------
__global__ __launch_bounds__(256) void reduce_partials(
    const float* __restrict__ partial, float* __restrict__ dots) {
  int i = blockIdx.x * 256 + threadIdx.x;  // 32768 total
  float s = 0.f;
#pragma unroll
  for (int c = 0; c < 8; ++c) s += partial[c * 32768 + i];
  dots[i] = s;
}

// ---------------- combine: W2T[b][o][e'] = sum_j dots[b,h,e'&31,j]*w_out[o,h*32+j]/n ----------------
__global__ __launch_bounds__(256) void combine_kernel(
    const float* __restrict__ dots, const float* __restrict__ Wout,
    unsigned short* __restrict__ W2T) {
  int bid = blockIdx.x;
  int b = bid >> 8, o = bid & 255;
  int e = threadIdx.x;
  int h = e >> 5;
  __shared__ float wrow[256];
  wrow[e] = Wout[o * 256 + e];
  __syncthreads();
  const float* dp = dots + (((size_t)b * 8 + h) * 32 + (e & 31)) * 32;
  const float* wp = wrow + h * 32;
  float s = 0.f;
#pragma unroll
  for (int j = 0; j < 32; ++j) s = fmaf(dp[j], wp[j], s);
  W2T[((size_t)b * 256 + o) * 256 + e] = f2bf(s * (1.0f / 16384.0f));
}

// ---------------- make_wfinal: WF[b][o][m] = sum_e W2T[b][o][e] * WqT[m][e] ----------------
__global__ __launch_bounds__(512) void make_wfinal(
    const unsigned short* __restrict__ W2T, const unsigned short* __restrict__ WqT,
    unsigned short* __restrict__ WF) {
  __shared__ __align__(16) char lds[49152];
  char* AsB[2] = {lds, lds + 16384};
  char* BsB[2] = {lds + 32768, lds + 40960};
  int bid = blockIdx.x;
  int b = bid >> 1, nh = bid & 1;
  int tid = threadIdx.x, lane = tid & 63, wid = tid >> 6;
  int wm = wid >> 1, wn = wid & 1;  // 4x2 waves: 64 o-rows x 64 m-cols each
  int lr = lane & 15, kg = lane >> 4;
  const char* Ag = (const char*)W2T + (size_t)b * 131072;
  const char* Bg = (const char*)WqT + (size_t)nh * 128 * 512;
  f32x4 acc[4][4] = {};
  stage_rows64<2>(Ag, 512, AsB[0], tid, 0);
  stage_rows64<1>(Bg, 512, BsB[0], tid, 0);
  __syncthreads();
  for (int kt = 0; kt < 8; ++kt) {
    int cur = kt & 1;
    if (kt < 7) {
      stage_rows64<2>(Ag, 512, AsB[cur ^ 1], tid, (kt + 1) * 64);
      stage_rows64<1>(Bg, 512, BsB[cur ^ 1], tid, (kt + 1) * 64);
    }
    bf16x8 af[4], bfr[4];
#pragma unroll
    for (int i = 0; i < 4; ++i) af[i] = fragB32(AsB[cur], wm * 64 + i * 16 + lr, kg);
#pragma unroll
    for (int j = 0; j < 4; ++j) bfr[j] = fragB32(BsB[cur], wn * 64 + j * 16 + lr, kg);
#pragma unroll
    for (int i = 0; i < 4; ++i)
#pragma unroll
      for (int j = 0; j < 4; ++j)
        acc[i][j] = __builtin_amdgcn_mfma_f32_16x16x32_bf16(bfr[j], af[i], acc[i][j], 0, 0, 0);
    __syncthreads();
  }
#pragma unroll
  for (int i = 0; i < 4; ++i) {
    int o = wm * 64 + i * 16 + lr;
#pragma unroll
    for (int j = 0; j < 4; ++j) {
      int m = nh * 128 + wn * 64 + j * 16 + kg * 4;
      uint2 pv;
      pv.x = (unsigned)f2bf(acc[i][j][0]) | ((unsigned)f2bf(acc[i][j][1]) << 16);
      pv.y = (unsigned)f2bf(acc[i][j][2]) | ((unsigned)f2bf(acc[i][j][3]) << 16);
      *(uint2*)(WF + (size_t)b * 65536 + (size_t)o * 256 + m) = pv;
    }
  }
}

// ---------------- final_gemm: out[t][o] = sum_m xb[t][m]*WF[b][o][m] + b_out[o] ----------------
__global__ __launch_bounds__(512) void final_gemm(
    const unsigned short* __restrict__ Xb, const unsigned short* __restrict__ WF,
    const float* __restrict__ bias, float* __restrict__ out) {
  __shared__ __align__(16) char lds[49152];
  char* AsB[2] = {lds, lds + 8192};
  char* BsB[2] = {lds + 16384, lds + 32768};
  int bid = blockIdx.x;
  int swz = (bid & 7) * 64 + (bid >> 3);
  int m0 = swz * 128;
  int b = swz >> 7;
  int tid = threadIdx.x, lane = tid & 63, wid = tid >> 6;
  int wm = wid >> 2, wn = wid & 3;  // 2x4 waves: 64 rows x 64 cols each (BN=256)
  int lr = lane & 15, kg = lane >> 4;
  const char* Ag = (const char*)Xb + (size_t)m0 * 512;
  const char* Bg = (const char*)WF + (size_t)b * 131072;
  f32x4 acc[4][4] = {};
  stage_rows64<1>(Ag, 512, AsB[0], tid, 0);
  stage_rows64<2>(Bg, 512, BsB[0], tid, 0);
  __syncthreads();
  for (int kt = 0; kt < 8; ++kt) {
    int cur = kt & 1;
    if (kt < 7) {
      stage_rows64<1>(Ag, 512, AsB[cur ^ 1], tid, (kt + 1) * 64);
      stage_rows64<2>(Bg, 512, BsB[cur ^ 1], tid, (kt + 1) * 64);
    }
    bf16x8 af[4], bfr[4];
#pragma unroll
    for (int i = 0; i < 4; ++i) af[i] = fragB32(AsB[cur], wm * 64 + i * 16 + lr, kg);
#pragma unroll
    for (int j = 0; j < 4; ++j) bfr[j] = fragB32(BsB[cur], wn * 64 + j * 16 + lr, kg);
#pragma unroll
    for (int i = 0; i < 4; ++i)
#pragma unroll
      for (int j = 0; j < 4; ++j)
        acc[i][j] = __builtin_amdgcn_mfma_f32_16x16x32_bf16(bfr[j], af[i], acc[i][j], 0, 0, 0);
    __syncthreads();
  }
#pragma unroll
  for (int i = 0; i < 4; ++i) {
    int row = m0 + wm * 64 + i * 16 + lr;
#pragma unroll
    for (int j = 0; j < 4; ++j) {
      int col = wn * 64 + j * 16 + kg * 4;
      f32x4 bo = *(const f32x4*)(bias + col);
      f32x4 v = acc[i][j] + bo;
      *(f32x4*)(out + (size_t)row * 256 + col) = v;
    }
  }
}

extern "C" void kernel_launch(void* const* d_in, const int* in_sizes, int n_in,
                              void* d_out, int out_size, void* d_ws, size_t ws_size,
                              hipStream_t stream) {
  const float* x     = (const float*)d_in[0];   // [4,16384,256]
  const float* w_qkv = (const float*)d_in[1];   // [768,256]
  const float* w_out = (const float*)d_in[2];   // [256,256]
  const float* b_out = (const float*)d_in[3];   // [256]

  char* ws = (char*)d_ws;
  unsigned short* Xb   = (unsigned short*)ws;                   // 33,554,432 B
  unsigned short* W2T  = (unsigned short*)(ws + 33554432);      //    524,288 B
  unsigned short* WF   = (unsigned short*)(ws + 34078720);      //    524,288 B
  unsigned short* Wkvb = (unsigned short*)(ws + 34603008);      //    262,144 B
  unsigned short* WqT  = (unsigned short*)(ws + 34865152);      //    131,072 B
  // small scratch lives in d_out (free until final_gemm overwrites all of it)
  float* partial = (float*)d_out;                               //  1,048,576 B
  float* dots    = (float*)((char*)d_out + 1048576);            //    131,072 B
  float* out     = (float*)d_out;

  hipMemsetAsync(partial, 0, 1048576, stream);
  prep_x<<<dim3(8192), dim3(256), 0, stream>>>(x, Xb);
  prep_w<<<dim3(132), dim3(256), 0, stream>>>(w_qkv, Wkvb, WqT);
  kv_dots<<<dim3(512), dim3(512), 0, stream>>>(Xb, Wkvb, partial);
  reduce_partials<<<dim3(128), dim3(256), 0, stream>>>(partial, dots);
  combine_kernel<<<dim3(1024), dim3(256), 0, stream>>>(dots, w_out, W2T);
  make_wfinal<<<dim3(8), dim3(512), 0, stream>>>(W2T, WqT, WF);
  final_gemm<<<dim3(512), dim3(512), 0, stream>>>(Xb, WF, b_out, out);
}